// Round 11
// baseline (367.514 us; speedup 1.0000x reference)
//
#include <hip/hip_runtime.h>
#include <math.h>

// Problem constants
#define B_SZ 256
#define S_SZ 6
#define D_SZ 10000
#define DP   10112      // D padded to 158*64
#define C_SZ 128
#define K_SZ 500
#define KP   512        // codebook rows padded (8 k-tiles of 64)
#define NIT  (DP / 64)  // 158 K-iterations (even)
#define THR  1.0f       // repair window; hi-only error bound <= ~0.29/value, 0.58/gap

typedef _Float16       half8 __attribute__((ext_vector_type(8)));
typedef float          f32x4 __attribute__((ext_vector_type(4)));
typedef unsigned int   u32x4v __attribute__((ext_vector_type(4)));
typedef unsigned short u16x4 __attribute__((ext_vector_type(4)));
typedef unsigned short u16x8 __attribute__((ext_vector_type(8)));
typedef unsigned int   u32x4b __attribute__((ext_vector_type(4)));

__device__ __forceinline__ void stage16(const void* g, void* l) {
    __builtin_amdgcn_global_load_lds(
        (const __attribute__((address_space(1))) unsigned int*)g,
        (__attribute__((address_space(3))) unsigned int*)l, 16, 0, 0);
}

// ---- prep: 2-D grid, row = blockIdx.y, 8 elems/thread, vector loads,
// zero integer divides. Single launch covers all three conversions.
// y in [0,KP): codebook row -> f16 zero-padded.
// y in [KP, KP+C_SZ): W_reg row -> f16 hi (near-ties repaired exactly later).
// y in [KP+C_SZ, KP+C_SZ+B_SZ): enc sign mask (0=+1, 0x8000=-1), sign-only:
//   sign(sin t) = + iff frac(t/2pi) < 0.5
//   sign(cos t) = + iff frac(t/2pi) < 0.25 or > 0.75
// product > 0 iff predicates agree; fp64-true signs (boundaries measure-zero).
__global__ void prep_fused(const float* __restrict__ cb, _Float16* __restrict__ cbp,
                           const float* __restrict__ wreg, _Float16* __restrict__ whi,
                           const float* __restrict__ x, const float* __restrict__ wp,
                           const float* __restrict__ bp, unsigned short* __restrict__ em) {
    const int d = blockIdx.x * 2048 + threadIdx.x * 8;
    if (d >= DP) return;
    const int y = blockIdx.y;
    if (y < KP) {                       // codebook row k = y
        const int k = y;
        half8 hv;
        if (k < K_SZ && d + 8 <= D_SZ) {
            const f32x4 v0 = *(const f32x4*)(cb + (size_t)k * D_SZ + d);
            const f32x4 v1 = *(const f32x4*)(cb + (size_t)k * D_SZ + d + 4);
            #pragma unroll
            for (int j = 0; j < 4; ++j) { hv[j] = (_Float16)v0[j]; hv[4 + j] = (_Float16)v1[j]; }
        } else {
            #pragma unroll
            for (int j = 0; j < 8; ++j)
                hv[j] = (_Float16)((k < K_SZ && d + j < D_SZ) ? cb[(size_t)k * D_SZ + d + j] : 0.0f);
        }
        *(half8*)(cbp + (size_t)k * DP + d) = hv;
    } else if (y < KP + C_SZ) {         // W_reg row c = y - KP
        const int c = y - KP;
        half8 hv;
        if (d + 8 <= D_SZ) {
            const f32x4 v0 = *(const f32x4*)(wreg + (size_t)c * D_SZ + d);
            const f32x4 v1 = *(const f32x4*)(wreg + (size_t)c * D_SZ + d + 4);
            #pragma unroll
            for (int j = 0; j < 4; ++j) { hv[j] = (_Float16)v0[j]; hv[4 + j] = (_Float16)v1[j]; }
        } else {
            #pragma unroll
            for (int j = 0; j < 8; ++j)
                hv[j] = (_Float16)((d + j < D_SZ) ? wreg[(size_t)c * D_SZ + d + j] : 0.0f);
        }
        *(half8*)(whi + (size_t)c * DP + d) = hv;
    } else {                            // enc row b = y - KP - C_SZ
        const int b = y - KP - C_SZ;
        u16x8 mv;
        if (d + 8 <= D_SZ) {
            float xv[S_SZ];
            #pragma unroll
            for (int s = 0; s < S_SZ; ++s) xv[s] = x[b * S_SZ + s];
            float wv[48];
            const float* wpd = wp + (size_t)d * S_SZ;
            #pragma unroll
            for (int q = 0; q < 12; ++q)
                *(f32x4*)(wv + q * 4) = *(const f32x4*)(wpd + q * 4);
            #pragma unroll
            for (int j = 0; j < 8; ++j) {
                double p = 0.0;
                #pragma unroll
                for (int s = 0; s < S_SZ; ++s)
                    p += (double)xv[s] * (double)wv[j * S_SZ + s];
                const double inv2pi = 0.15915494309189535;
                double t1 = p * inv2pi;
                double f1 = t1 - floor(t1);                     // sin(p) sign
                double t2 = (p + (double)bp[d + j]) * inv2pi;
                double f2 = t2 - floor(t2);                     // cos(p+b) sign
                bool sin_pos = (f1 < 0.5);
                bool cos_pos = (f2 < 0.25) || (f2 > 0.75);
                mv[j] = (sin_pos == cos_pos) ? (unsigned short)0u : (unsigned short)0x8000u;
            }
        } else {
            #pragma unroll
            for (int j = 0; j < 8; ++j) mv[j] = 0;  // d >= 10000 pad region
        }
        *(u16x8*)(em + (size_t)b * DP + d) = mv;
    }
}

// ---- main (R11): R6 gemm with MINIMAL unroll-2 — loop body duplicated with
// the LDS buffer index as a compile-time literal. Nothing else changed from
// the proven R6 body (R5's spill came from bundled pointer-hoisting+setprio,
// not from unrolling: barriers between phases stop cross-phase ds_read
// hoisting, so fragment pressure stays at R6's 116 VGPR). Effect: the 20
// cur-indexed ds_read v_adds become immediate offsets -> fewer VALU issues
// in a 99%-issue-saturated loop.
__global__ __launch_bounds__(256, 2) void gemm_sim(
    const _Float16* __restrict__ whi, const _Float16* __restrict__ cbp,
    const unsigned short* __restrict__ em, _Float16* __restrict__ simh)
{
    const int kt = blockIdx.x >> 1;   // 0..7  k-tile (64 codebook rows)
    const int ct = blockIdx.x & 1;    // 0..1  c-tile (64 classes)
    const int bg = blockIdx.y;        // 0..31 batch group (8 batches)
    const int tid  = threadIdx.x;
    const int wave = tid >> 6;        // owns batches {2*wave, 2*wave+1}
    const int lane = tid & 63;
    const int quad = lane >> 4;
    const int col  = lane & 15;

    __shared__ __align__(16) _Float16 s_whi[2][64 * 64];
    __shared__ __align__(16) _Float16 s_cb [2][64 * 64];
    __shared__ __align__(16) unsigned short s_mask[2][8 * 64];

    f32x4 acc[2][4][4];
    #pragma unroll
    for (int b = 0; b < 2; ++b)
        #pragma unroll
        for (int m = 0; m < 4; ++m)
            #pragma unroll
            for (int n = 0; n < 4; ++n)
                acc[b][m][n] = (f32x4){0.f, 0.f, 0.f, 0.f};

    const int c0  = ct * 64;
    const int kr0 = kt * 64;
    const int bg8 = bg * 8;

    // staging geometry: slot e: row=e>>3, pos p=e&7; global chunk = p^(row&7)
    size_t abase[2], bbase[2];
    int soff[2];
    #pragma unroll
    for (int s = 0; s < 2; ++s) {
        int e = s * 256 + tid;          // 0..511
        int row = e >> 3;
        int p = e & 7;
        int gcol = (p ^ (row & 7)) * 8;
        abase[s] = (size_t)(c0 + row) * DP + gcol;
        bbase[s] = (size_t)(kr0 + row) * DP + gcol;
        soff[s] = e * 8;
    }
    const size_t embase = (size_t)(bg8 + (tid >> 3)) * DP + (tid & 7) * 8;

    auto STAGE = [&](int buf, int kb) {
        const int k0 = kb * 64;
        #pragma unroll
        for (int s = 0; s < 2; ++s) {
            stage16(whi + abase[s] + k0, &s_whi[buf][soff[s]]);
            stage16(cbp + bbase[s] + k0, &s_cb [buf][soff[s]]);
        }
        if (tid < 64)  // 8 b x 64 ushort masks = 1 KiB; lane-linear LDS dest
            stage16(em + embase + k0, &s_mask[buf][tid * 8]);
    };

// COMPUTE(BUF): verbatim R6 inner body, BUF a literal 0/1.
#define COMPUTE(BUF)                                                            \
    {                                                                           \
        u32x4v ah[2][4], br[2][4], mr[2][2];                                    \
        _Pragma("unroll") for (int k2 = 0; k2 < 2; ++k2) {                      \
            const int chunk = k2 * 4 + quad;                                    \
            const int sw    = (chunk ^ (col & 7)) * 8;                          \
            _Pragma("unroll") for (int m = 0; m < 4; ++m)                       \
                ah[k2][m] = *(const u32x4v*)(&s_whi[BUF][(m * 16 + col) * 64 + sw]); \
            _Pragma("unroll") for (int n = 0; n < 4; ++n)                       \
                br[k2][n] = *(const u32x4v*)(&s_cb[BUF][(n * 16 + col) * 64 + sw]); \
            _Pragma("unroll") for (int b = 0; b < 2; ++b)                       \
                mr[k2][b] = *(const u32x4v*)(&s_mask[BUF][(wave * 2 + b) * 64 + chunk * 8]); \
        }                                                                       \
        _Pragma("unroll") for (int k2 = 0; k2 < 2; ++k2) {                      \
            _Pragma("unroll") for (int b = 0; b < 2; ++b) {                     \
                half8 bs[4];                                                    \
                _Pragma("unroll") for (int n = 0; n < 4; ++n)                   \
                    bs[n] = __builtin_bit_cast(half8, br[k2][n] ^ mr[k2][b]);   \
                _Pragma("unroll") for (int m = 0; m < 4; ++m) {                 \
                    half8 a = __builtin_bit_cast(half8, ah[k2][m]);             \
                    _Pragma("unroll") for (int n = 0; n < 4; ++n)               \
                        acc[b][m][n] = __builtin_amdgcn_mfma_f32_16x16x32_f16(  \
                            a, bs[n], acc[b][m][n], 0, 0, 0);                   \
                }                                                               \
            }                                                                   \
        }                                                                       \
    }

    STAGE(0, 0);
    __syncthreads();   // vmcnt(0) drain: tile 0 resident

    for (int p = 0; p < NIT / 2; ++p) {
        STAGE(1, 2 * p + 1);          // buf1 loads fly under COMPUTE(0)
        COMPUTE(0);
        __syncthreads();              // buf1 landed; buf0 reads done
        if (2 * p + 2 < NIT) STAGE(0, 2 * p + 2);
        COMPUTE(1);
        __syncthreads();              // buf0 landed; buf1 reads done
    }
#undef COMPUTE

    // ---- epilogue: store f16 sim tile. C/D layout (16x16): col=lane&15 (k),
    // row = quad*4 + reg (c). Each wave stores its 2 batches' full 64x64 tile.
    #pragma unroll
    for (int b = 0; b < 2; ++b) {
        const size_t base = ((size_t)(bg8 + wave * 2 + b) * C_SZ + (size_t)c0) * KP;
        #pragma unroll
        for (int m = 0; m < 4; ++m)
            #pragma unroll
            for (int n = 0; n < 4; ++n) {
                const int kg = kr0 + n * 16 + col;
                #pragma unroll
                for (int r = 0; r < 4; ++r) {
                    const int cl = m * 16 + quad * 4 + r;
                    simh[base + (size_t)cl * KP + kg] = (_Float16)acc[b][m][n][r];
                }
            }
    }
}

// ---- pass 2: argmax + inline repair (single launch). Wave per (b,c) row:
// top-2 over k<500 from the f16 sims. gap >= THR is provably safe
// (2 x 0.29 error bound < 1.0) -> use f16 argmax. Else the SAME wave does the
// exact fp64 recompute of the ballot-selected candidates (vf[] already in
// registers). Branch is wave-uniform; ~3% of waves take the slow path.
__global__ __launch_bounds__(256) void argmax_repair(
    const _Float16* __restrict__ simh, const unsigned short* __restrict__ em,
    const float* __restrict__ wreg, const float* __restrict__ cb,
    float* __restrict__ out)
{
    const int wave = threadIdx.x >> 6, lane = threadIdx.x & 63;
    const int row = blockIdx.x * 4 + wave;       // 8192 blocks x 4 rows
    const half8 v = *(const half8*)(simh + (size_t)row * KP + lane * 8);
    float vf[8];
    float bv = -3.0e38f, bv2 = -3.0e38f; int bk = 0x7fffffff;
    #pragma unroll
    for (int j = 0; j < 8; ++j) {
        const int k = lane * 8 + j;
        vf[j] = (k < K_SZ) ? (float)v[j] : -3.0e38f;
        if (vf[j] > bv)       { bv2 = bv; bv = vf[j]; bk = k; }
        else if (vf[j] > bv2) { bv2 = vf[j]; }
    }
    #pragma unroll
    for (int off = 1; off < 64; off <<= 1) {
        const float ov  = __shfl_xor(bv,  off, 64);
        const int   ok  = __shfl_xor(bk,  off, 64);
        const float ov2 = __shfl_xor(bv2, off, 64);
        if (ov > bv || (ov == bv && ok < bk)) { bv2 = fmaxf(bv, ov2); bv = ov; bk = ok; }
        else                                  { bv2 = fmaxf(ov, bv2); }
    }

    int bestk = bk;
    if (bv - bv2 < THR) {     // wave-uniform: exact fp64 repair of candidates
        const int b = row >> 7, c = row & 127;
        const float thr = bv - THR;    // true argmax provably within THR of max
        const float* wr = wreg + (size_t)c * D_SZ;
        const unsigned short* eb = em + (size_t)b * DP;
        double best = -1.0e300; bestk = 0x7fffffff;
        #pragma unroll
        for (int j = 0; j < 8; ++j) {
            unsigned long long bal = __ballot(vf[j] >= thr);
            while (bal) {
                const int l = __ffsll((long long)bal) - 1;
                bal &= bal - 1;
                const int k = l * 8 + j;          // candidate codebook row
                const float* ck = cb + (size_t)k * D_SZ;
                double s0 = 0.0, s1 = 0.0, s2 = 0.0, s3 = 0.0;
                // D_SZ % 4 == 0, so d<D_SZ with d%4==0 implies full float4 in-bounds
                for (int d = lane * 4; d < D_SZ; d += 256) {
                    const f32x4 w  = *(const f32x4*)(wr + d);
                    const u16x4 e4 = *(const u16x4*)(eb + d);
                    const f32x4 cw = *(const f32x4*)(ck + d);
                    const u32x4b wb = __builtin_bit_cast(u32x4b, w);
                    const u32x4b cbits = __builtin_bit_cast(u32x4b, cw);
                    u32x4b sb;
                    #pragma unroll
                    for (int q = 0; q < 4; ++q)
                        sb[q] = wb[q] ^ ((((unsigned int)e4[q] << 16) ^ cbits[q]) & 0x80000000u);
                    const f32x4 ws = __builtin_bit_cast(f32x4, sb);
                    s0 += (double)ws[0];
                    s1 += (double)ws[1];
                    s2 += (double)ws[2];
                    s3 += (double)ws[3];
                }
                double s = (s0 + s1) + (s2 + s3);
                #pragma unroll
                for (int off = 1; off < 64; off <<= 1)
                    s += __shfl_xor(s, off, 64);
                if (s > best || (s == best && k < bestk)) { best = s; bestk = k; }
            }
        }
    }
    if (lane == 0)
        out[row] = (float)bestk * (61.5f / 499.0f) - 19.9f;
}

extern "C" void kernel_launch(void* const* d_in, const int* in_sizes, int n_in,
                              void* d_out, int out_size, void* d_ws, size_t ws_size,
                              hipStream_t stream) {
    const float* x    = (const float*)d_in[0];
    const float* wp   = (const float*)d_in[1];
    const float* bp   = (const float*)d_in[2];
    const float* wreg = (const float*)d_in[3];
    const float* cb   = (const float*)d_in[4];
    float* out = (float*)d_out;

    char* ws = (char*)d_ws;
    size_t o = 0;
    auto take = [&](size_t bytes) -> char* {
        o = (o + 255) & ~(size_t)255;
        char* p = ws + o;
        o += bytes;
        return p;
    };
    _Float16* whi       = (_Float16*)take(sizeof(_Float16) * C_SZ * DP);
    _Float16* cbp       = (_Float16*)take(sizeof(_Float16) * KP * DP);
    unsigned short* em  = (unsigned short*)take(sizeof(unsigned short) * B_SZ * DP);
    _Float16* simh      = (_Float16*)take(sizeof(_Float16) * (size_t)B_SZ * C_SZ * KP);
    (void)ws_size; (void)in_sizes; (void)n_in; (void)out_size;

    // single prep launch: x covers DP in 2048-elem slabs (5), y = 896 rows
    dim3 gp(5, KP + C_SZ + B_SZ);
    prep_fused<<<gp, 256, 0, stream>>>(cb, cbp, wreg, whi, x, wp, bp, em);

    dim3 g(16, 32);  // x: kt*2+ct, y: batch group of 8 -> 512 blocks = 2/CU exactly
    gemm_sim<<<g, 256, 0, stream>>>(whi, cbp, em, simh);

    // fused argmax + inline exact repair: 8192 blocks x 4 rows = 32768 rows
    argmax_repair<<<(B_SZ * C_SZ) / 4, 256, 0, stream>>>(simh, em, wreg, cb, out);
}

// Round 12
// 352.089 us; speedup vs baseline: 1.0438x; 1.0438x over previous
//
#include <hip/hip_runtime.h>
#include <math.h>

// Problem constants
#define B_SZ 256
#define S_SZ 6
#define D_SZ 10000
#define DP   10112      // D padded to 158*64
#define C_SZ 128
#define K_SZ 500
#define KP   512        // codebook rows padded (8 k-tiles of 64)
#define NIT  (DP / 64)  // 158 K-iterations
#define THR  1.0f       // repair window; hi-only error bound <= ~0.29/value, 0.58/gap

typedef _Float16       half8 __attribute__((ext_vector_type(8)));
typedef float          f32x4 __attribute__((ext_vector_type(4)));
typedef unsigned int   u32x4v __attribute__((ext_vector_type(4)));
typedef unsigned short u16x4 __attribute__((ext_vector_type(4)));
typedef unsigned short u16x8 __attribute__((ext_vector_type(8)));
typedef unsigned int   u32x4b __attribute__((ext_vector_type(4)));

__device__ __forceinline__ void stage16(const void* g, void* l) {
    __builtin_amdgcn_global_load_lds(
        (const __attribute__((address_space(1))) unsigned int*)g,
        (__attribute__((address_space(3))) unsigned int*)l, 16, 0, 0);
}

// ---- prep: 2-D grid, row = blockIdx.y, 8 elems/thread, vector loads,
// zero integer divides. Single launch covers all three conversions.
// y in [0,KP): codebook row -> f16 zero-padded.
// y in [KP, KP+C_SZ): W_reg row -> f16 hi (near-ties repaired exactly later).
// y in [KP+C_SZ, KP+C_SZ+B_SZ): enc sign mask (0=+1, 0x8000=-1), sign-only:
//   sign(sin t) = + iff frac(t/2pi) < 0.5
//   sign(cos t) = + iff frac(t/2pi) < 0.25 or > 0.75
// product > 0 iff predicates agree; fp64-true signs (boundaries measure-zero).
__global__ void prep_fused(const float* __restrict__ cb, _Float16* __restrict__ cbp,
                           const float* __restrict__ wreg, _Float16* __restrict__ whi,
                           const float* __restrict__ x, const float* __restrict__ wp,
                           const float* __restrict__ bp, unsigned short* __restrict__ em) {
    const int d = blockIdx.x * 2048 + threadIdx.x * 8;
    if (d >= DP) return;
    const int y = blockIdx.y;
    if (y < KP) {                       // codebook row k = y
        const int k = y;
        half8 hv;
        if (k < K_SZ && d + 8 <= D_SZ) {
            const f32x4 v0 = *(const f32x4*)(cb + (size_t)k * D_SZ + d);
            const f32x4 v1 = *(const f32x4*)(cb + (size_t)k * D_SZ + d + 4);
            #pragma unroll
            for (int j = 0; j < 4; ++j) { hv[j] = (_Float16)v0[j]; hv[4 + j] = (_Float16)v1[j]; }
        } else {
            #pragma unroll
            for (int j = 0; j < 8; ++j)
                hv[j] = (_Float16)((k < K_SZ && d + j < D_SZ) ? cb[(size_t)k * D_SZ + d + j] : 0.0f);
        }
        *(half8*)(cbp + (size_t)k * DP + d) = hv;
    } else if (y < KP + C_SZ) {         // W_reg row c = y - KP
        const int c = y - KP;
        half8 hv;
        if (d + 8 <= D_SZ) {
            const f32x4 v0 = *(const f32x4*)(wreg + (size_t)c * D_SZ + d);
            const f32x4 v1 = *(const f32x4*)(wreg + (size_t)c * D_SZ + d + 4);
            #pragma unroll
            for (int j = 0; j < 4; ++j) { hv[j] = (_Float16)v0[j]; hv[4 + j] = (_Float16)v1[j]; }
        } else {
            #pragma unroll
            for (int j = 0; j < 8; ++j)
                hv[j] = (_Float16)((d + j < D_SZ) ? wreg[(size_t)c * D_SZ + d + j] : 0.0f);
        }
        *(half8*)(whi + (size_t)c * DP + d) = hv;
    } else {                            // enc row b = y - KP - C_SZ
        const int b = y - KP - C_SZ;
        u16x8 mv;
        if (d + 8 <= D_SZ) {
            float xv[S_SZ];
            #pragma unroll
            for (int s = 0; s < S_SZ; ++s) xv[s] = x[b * S_SZ + s];
            float wv[48];
            const float* wpd = wp + (size_t)d * S_SZ;
            #pragma unroll
            for (int q = 0; q < 12; ++q)
                *(f32x4*)(wv + q * 4) = *(const f32x4*)(wpd + q * 4);
            #pragma unroll
            for (int j = 0; j < 8; ++j) {
                double p = 0.0;
                #pragma unroll
                for (int s = 0; s < S_SZ; ++s)
                    p += (double)xv[s] * (double)wv[j * S_SZ + s];
                const double inv2pi = 0.15915494309189535;
                double t1 = p * inv2pi;
                double f1 = t1 - floor(t1);                     // sin(p) sign
                double t2 = (p + (double)bp[d + j]) * inv2pi;
                double f2 = t2 - floor(t2);                     // cos(p+b) sign
                bool sin_pos = (f1 < 0.5);
                bool cos_pos = (f2 < 0.25) || (f2 > 0.75);
                mv[j] = (sin_pos == cos_pos) ? (unsigned short)0u : (unsigned short)0x8000u;
            }
        } else {
            #pragma unroll
            for (int j = 0; j < 8; ++j) mv[j] = 0;  // d >= 10000 pad region
        }
        *(u16x8*)(em + (size_t)b * DP + d) = mv;
    }
}

// ---- main: byte-exact R6/R10 gemm (best measured: 251-253 us, MfmaUtil 62%,
// VALU 37% -> 99% issue-saturated, 0 bank conflicts, no spill).
// Closed alternatives (all regressed, counter-diagnosed):
//   R5  unroll-2 + hoisted ptrs + setprio  -> spill (+15 MB scratch)
//   R7  32x32x16 row-major LDS             -> 2.07e7 bank-conflict cycles
//   R8  BK=128                             -> spill + conflicts
//   R9  32x32x16 chunk-major LDS           -> lgkmcnt dead-stall (81% issue)
//   R11 minimal unroll-2                   -> spill (WRITE 32.8->46.6 MB)
// The runtime-cur 2-barrier schedule is this algorithm's local optimum;
// remaining VALU (sign-XOR + addressing) is not removable without spilling.
__global__ __launch_bounds__(256, 2) void gemm_sim(
    const _Float16* __restrict__ whi, const _Float16* __restrict__ cbp,
    const unsigned short* __restrict__ em, _Float16* __restrict__ simh)
{
    const int kt = blockIdx.x >> 1;   // 0..7  k-tile (64 codebook rows)
    const int ct = blockIdx.x & 1;    // 0..1  c-tile (64 classes)
    const int bg = blockIdx.y;        // 0..31 batch group (8 batches)
    const int tid  = threadIdx.x;
    const int wave = tid >> 6;        // owns batches {2*wave, 2*wave+1}
    const int lane = tid & 63;
    const int quad = lane >> 4;
    const int col  = lane & 15;

    __shared__ __align__(16) _Float16 s_whi[2][64 * 64];
    __shared__ __align__(16) _Float16 s_cb [2][64 * 64];
    __shared__ __align__(16) unsigned short s_mask[2][8 * 64];

    f32x4 acc[2][4][4];
    #pragma unroll
    for (int b = 0; b < 2; ++b)
        #pragma unroll
        for (int m = 0; m < 4; ++m)
            #pragma unroll
            for (int n = 0; n < 4; ++n)
                acc[b][m][n] = (f32x4){0.f, 0.f, 0.f, 0.f};

    const int c0  = ct * 64;
    const int kr0 = kt * 64;
    const int bg8 = bg * 8;

    // staging geometry: slot e: row=e>>3, pos p=e&7; global chunk = p^(row&7)
    size_t abase[2], bbase[2];
    int soff[2];
    #pragma unroll
    for (int s = 0; s < 2; ++s) {
        int e = s * 256 + tid;          // 0..511
        int row = e >> 3;
        int p = e & 7;
        int gcol = (p ^ (row & 7)) * 8;
        abase[s] = (size_t)(c0 + row) * DP + gcol;
        bbase[s] = (size_t)(kr0 + row) * DP + gcol;
        soff[s] = e * 8;
    }
    const size_t embase = (size_t)(bg8 + (tid >> 3)) * DP + (tid & 7) * 8;

    auto STAGE = [&](int buf, int kb) {
        const int k0 = kb * 64;
        #pragma unroll
        for (int s = 0; s < 2; ++s) {
            stage16(whi + abase[s] + k0, &s_whi[buf][soff[s]]);
            stage16(cbp + bbase[s] + k0, &s_cb [buf][soff[s]]);
        }
        if (tid < 64)  // 8 b x 64 ushort masks = 1 KiB; lane-linear LDS dest
            stage16(em + embase + k0, &s_mask[buf][tid * 8]);
    };

    STAGE(0, 0);
    __syncthreads();   // vmcnt(0) drain: tile 0 resident
    int cur = 0;

    for (int kb = 0; kb < NIT; ++kb) {
        if (kb + 1 < NIT) STAGE(cur ^ 1, kb + 1);   // next tile in flight under MFMAs

        // preload both k2 phases' fragments: later loads stay in flight
        // (lgkmcnt>0) while earlier MFMAs run.
        u32x4v ah[2][4], br[2][4], mr[2][2];
        #pragma unroll
        for (int k2 = 0; k2 < 2; ++k2) {
            const int chunk = k2 * 4 + quad;
            const int sw    = (chunk ^ (col & 7)) * 8;
            #pragma unroll
            for (int m = 0; m < 4; ++m)
                ah[k2][m] = *(const u32x4v*)(&s_whi[cur][(m * 16 + col) * 64 + sw]);
            #pragma unroll
            for (int n = 0; n < 4; ++n)
                br[k2][n] = *(const u32x4v*)(&s_cb[cur][(n * 16 + col) * 64 + sw]);
            #pragma unroll
            for (int b = 0; b < 2; ++b)
                mr[k2][b] = *(const u32x4v*)(&s_mask[cur][(wave * 2 + b) * 64 + chunk * 8]);
        }
        #pragma unroll
        for (int k2 = 0; k2 < 2; ++k2) {
            #pragma unroll
            for (int b = 0; b < 2; ++b) {
                half8 bs[4];
                #pragma unroll
                for (int n = 0; n < 4; ++n)
                    bs[n] = __builtin_bit_cast(half8, br[k2][n] ^ mr[k2][b]);
                #pragma unroll
                for (int m = 0; m < 4; ++m) {
                    half8 a = __builtin_bit_cast(half8, ah[k2][m]);
                    #pragma unroll
                    for (int n = 0; n < 4; ++n)
                        acc[b][m][n] = __builtin_amdgcn_mfma_f32_16x16x32_f16(a, bs[n], acc[b][m][n], 0, 0, 0);
                }
            }
        }
        __syncthreads();   // vmcnt(0)+lgkmcnt(0) drain: next tile ready, reads done
        cur ^= 1;
    }

    // ---- epilogue: store f16 sim tile. C/D layout (16x16): col=lane&15 (k),
    // row = quad*4 + reg (c). Each wave stores its 2 batches' full 64x64 tile.
    #pragma unroll
    for (int b = 0; b < 2; ++b) {
        const size_t base = ((size_t)(bg8 + wave * 2 + b) * C_SZ + (size_t)c0) * KP;
        #pragma unroll
        for (int m = 0; m < 4; ++m)
            #pragma unroll
            for (int n = 0; n < 4; ++n) {
                const int kg = kr0 + n * 16 + col;
                #pragma unroll
                for (int r = 0; r < 4; ++r) {
                    const int cl = m * 16 + quad * 4 + r;
                    simh[base + (size_t)cl * KP + kg] = (_Float16)acc[b][m][n][r];
                }
            }
    }
}

// ---- pass 2: argmax + inline repair (single launch). Wave per (b,c) row:
// top-2 over k<500 from the f16 sims. gap >= THR is provably safe
// (2 x 0.29 error bound < 1.0) -> use f16 argmax. Else the SAME wave does the
// exact fp64 recompute of the ballot-selected candidates (vf[] already in
// registers). Branch is wave-uniform; ~3% of waves take the slow path.
__global__ __launch_bounds__(256) void argmax_repair(
    const _Float16* __restrict__ simh, const unsigned short* __restrict__ em,
    const float* __restrict__ wreg, const float* __restrict__ cb,
    float* __restrict__ out)
{
    const int wave = threadIdx.x >> 6, lane = threadIdx.x & 63;
    const int row = blockIdx.x * 4 + wave;       // 8192 blocks x 4 rows
    const half8 v = *(const half8*)(simh + (size_t)row * KP + lane * 8);
    float vf[8];
    float bv = -3.0e38f, bv2 = -3.0e38f; int bk = 0x7fffffff;
    #pragma unroll
    for (int j = 0; j < 8; ++j) {
        const int k = lane * 8 + j;
        vf[j] = (k < K_SZ) ? (float)v[j] : -3.0e38f;
        if (vf[j] > bv)       { bv2 = bv; bv = vf[j]; bk = k; }
        else if (vf[j] > bv2) { bv2 = vf[j]; }
    }
    #pragma unroll
    for (int off = 1; off < 64; off <<= 1) {
        const float ov  = __shfl_xor(bv,  off, 64);
        const int   ok  = __shfl_xor(bk,  off, 64);
        const float ov2 = __shfl_xor(bv2, off, 64);
        if (ov > bv || (ov == bv && ok < bk)) { bv2 = fmaxf(bv, ov2); bv = ov; bk = ok; }
        else                                  { bv2 = fmaxf(ov, bv2); }
    }

    int bestk = bk;
    if (bv - bv2 < THR) {     // wave-uniform: exact fp64 repair of candidates
        const int b = row >> 7, c = row & 127;
        const float thr = bv - THR;    // true argmax provably within THR of max
        const float* wr = wreg + (size_t)c * D_SZ;
        const unsigned short* eb = em + (size_t)b * DP;
        double best = -1.0e300; bestk = 0x7fffffff;
        #pragma unroll
        for (int j = 0; j < 8; ++j) {
            unsigned long long bal = __ballot(vf[j] >= thr);
            while (bal) {
                const int l = __ffsll((long long)bal) - 1;
                bal &= bal - 1;
                const int k = l * 8 + j;          // candidate codebook row
                const float* ck = cb + (size_t)k * D_SZ;
                double s0 = 0.0, s1 = 0.0, s2 = 0.0, s3 = 0.0;
                // D_SZ % 4 == 0, so d<D_SZ with d%4==0 implies full float4 in-bounds
                for (int d = lane * 4; d < D_SZ; d += 256) {
                    const f32x4 w  = *(const f32x4*)(wr + d);
                    const u16x4 e4 = *(const u16x4*)(eb + d);
                    const f32x4 cw = *(const f32x4*)(ck + d);
                    const u32x4b wb = __builtin_bit_cast(u32x4b, w);
                    const u32x4b cbits = __builtin_bit_cast(u32x4b, cw);
                    u32x4b sb;
                    #pragma unroll
                    for (int q = 0; q < 4; ++q)
                        sb[q] = wb[q] ^ ((((unsigned int)e4[q] << 16) ^ cbits[q]) & 0x80000000u);
                    const f32x4 ws = __builtin_bit_cast(f32x4, sb);
                    s0 += (double)ws[0];
                    s1 += (double)ws[1];
                    s2 += (double)ws[2];
                    s3 += (double)ws[3];
                }
                double s = (s0 + s1) + (s2 + s3);
                #pragma unroll
                for (int off = 1; off < 64; off <<= 1)
                    s += __shfl_xor(s, off, 64);
                if (s > best || (s == best && k < bestk)) { best = s; bestk = k; }
            }
        }
    }
    if (lane == 0)
        out[row] = (float)bestk * (61.5f / 499.0f) - 19.9f;
}

extern "C" void kernel_launch(void* const* d_in, const int* in_sizes, int n_in,
                              void* d_out, int out_size, void* d_ws, size_t ws_size,
                              hipStream_t stream) {
    const float* x    = (const float*)d_in[0];
    const float* wp   = (const float*)d_in[1];
    const float* bp   = (const float*)d_in[2];
    const float* wreg = (const float*)d_in[3];
    const float* cb   = (const float*)d_in[4];
    float* out = (float*)d_out;

    char* ws = (char*)d_ws;
    size_t o = 0;
    auto take = [&](size_t bytes) -> char* {
        o = (o + 255) & ~(size_t)255;
        char* p = ws + o;
        o += bytes;
        return p;
    };
    _Float16* whi       = (_Float16*)take(sizeof(_Float16) * C_SZ * DP);
    _Float16* cbp       = (_Float16*)take(sizeof(_Float16) * KP * DP);
    unsigned short* em  = (unsigned short*)take(sizeof(unsigned short) * B_SZ * DP);
    _Float16* simh      = (_Float16*)take(sizeof(_Float16) * (size_t)B_SZ * C_SZ * KP);
    (void)ws_size; (void)in_sizes; (void)n_in; (void)out_size;

    // single prep launch: x covers DP in 2048-elem slabs (5), y = 896 rows
    dim3 gp(5, KP + C_SZ + B_SZ);
    prep_fused<<<gp, 256, 0, stream>>>(cb, cbp, wreg, whi, x, wp, bp, em);

    dim3 g(16, 32);  // x: kt*2+ct, y: batch group of 8 -> 512 blocks = 2/CU exactly
    gemm_sim<<<g, 256, 0, stream>>>(whi, cbp, em, simh);

    // fused argmax + inline exact repair: 8192 blocks x 4 rows = 32768 rows
    argmax_repair<<<(B_SZ * C_SZ) / 4, 256, 0, stream>>>(simh, em, wreg, cb, out);
}